// Round 12
// baseline (291.129 us; speedup 1.0000x reference)
//
#include <hip/hip_runtime.h>
#include <hip/hip_bf16.h>
#include <float.h>
#include <math.h>

typedef float f32x4 __attribute__((ext_vector_type(4)));
typedef short short8 __attribute__((ext_vector_type(8)));
typedef unsigned int uint32;

#define NB 4
#define SQ 4096
#define DM 4096
#define DH 128
#define LOG2E 1.44269504088896f
#define SCALE 0.0883883476483184f   // 1/sqrt(128)
#define SCL2 (SCALE * LOG2E)        // fold into log2 domain

__device__ __forceinline__ unsigned short f2bf(float f) {
  union { float f; unsigned u; } x; x.f = f;
  unsigned r = x.u + 0x7FFFu + ((x.u >> 16) & 1u);
  return (unsigned short)(r >> 16);
}

__device__ __forceinline__ uint2 cvt4(float4 f) {
  uint2 u;
  asm("v_cvt_pk_bf16_f32 %0, %1, %2" : "=v"(u.x) : "v"(f.x), "v"(f.y));
  asm("v_cvt_pk_bf16_f32 %0, %1, %2" : "=v"(u.y) : "v"(f.z), "v"(f.w));
  return u;
}

#define GLD16(g, l) __builtin_amdgcn_global_load_lds( \
    (const __attribute__((address_space(1))) void*)(g), \
    (__attribute__((address_space(3))) void*)(l), 16, 0, 0)

// ---------------- kernel 1: pack weights (bf16) + bias (f32) ----------------
__global__ void cast_w_kernel(const float* __restrict__ wq, const float* __restrict__ wk,
                              const float* __restrict__ wv, const float* __restrict__ bq,
                              const float* __restrict__ bk, const float* __restrict__ bv,
                              unsigned short* __restrict__ wb, float* __restrict__ biasws) {
  int t = blockIdx.x * 256 + threadIdx.x;  // 0..196607, each handles 8 elems
  int base = t * 8;
  int n = base >> 12;       // output row 0..383 (q:0-127, k:128-255, v:256-383)
  int d = base & 4095;
  const float* src = (n < 128) ? (wq + (size_t)n * DM)
                   : (n < 256) ? (wk + (size_t)(n - 128) * DM)
                               : (wv + (size_t)(n - 256) * DM);
  float4 f0 = *(const float4*)(src + d);
  float4 f1 = *(const float4*)(src + d + 4);
  short8 v;
  v[0] = (short)f2bf(f0.x); v[1] = (short)f2bf(f0.y);
  v[2] = (short)f2bf(f0.z); v[3] = (short)f2bf(f0.w);
  v[4] = (short)f2bf(f1.x); v[5] = (short)f2bf(f1.y);
  v[6] = (short)f2bf(f1.z); v[7] = (short)f2bf(f1.w);
  *(short8*)(wb + base) = v;
  if (t < 384) biasws[t] = (t < 128) ? bq[t] : (t < 256) ? bk[t - 128] : bv[t - 256];
}

// ---------------- kernel 1b: x f32 -> bf16 (done ONCE; removes cvt from the
// GEMM K-loop where 6 sibling blocks each re-converted the same data) --------
__global__ __launch_bounds__(256) void cast_x_kernel(const float* __restrict__ x,
                                                     unsigned short* __restrict__ xb) {
  const size_t total = (size_t)NB * SQ * DM;
  const size_t stride = (size_t)gridDim.x * 256 * 8;
  for (size_t i = ((size_t)blockIdx.x * 256 + threadIdx.x) * 8; i < total; i += stride) {
    float4 f0 = *(const float4*)(x + i);
    float4 f1 = *(const float4*)(x + i + 4);
    uint2 u0 = cvt4(f0), u1 = cvt4(f1);
    uint4 u; u.x = u0.x; u.y = u0.y; u.z = u1.x; u.w = u1.y;
    *(uint4*)(xb + i) = u;
  }
}

// ---------------- kernel 2A: split-K GEMM, PURE m97 structure ----------------
// BM=128, BN=128 (= one head), BK=64, K split in 2 halves of 2048 (32 iters).
// 256 threads = 4 waves (2x2), wave-tile 64x64 (acc 4x4). BOTH operands bf16
// staged via global_load_lds (pre-swizzled source, linear LDS dest, rule #21).
// Inner loop = m97's: 8 GLD16 + 2 barriers + 2x(8 ds_read_b128 + 16 MFMA).
// Single-buffered 32 KB LDS; 3 blocks/CU co-residency hides the drains (m114).
// Grid 768 = 128m x 3head x 2ks; XCD mapping co-locates one m-tile's 6
// sibling blocks (xb L2-shared). Partials f32 -> pbuf; bias+RoPE in reduce.
__global__ __launch_bounds__(256, 3) void gemm_qkv_split(
    const unsigned short* __restrict__ xb, const unsigned short* __restrict__ wb,
    float* __restrict__ pbuf) {
  __shared__ __align__(16) short Alds[128 * 64];   // 16 KB bf16, XOR-swizzled
  __shared__ __align__(16) short Blds[128 * 64];   // 16 KB bf16, XOR-swizzled
  const int tid = threadIdx.x;
  const int l = tid & 63, w = tid >> 6;
  const int wm = w >> 1, wn = w & 1;
  const int l15 = l & 15, lg = l >> 4;

  const int bid = blockIdx.x;
  const int xcd = bid & 7, j = bid >> 3;
  const int mloc = j / 6, sub = j - mloc * 6;
  const int ns = sub >> 1, ks = sub & 1;
  const int m0 = (xcd * 16 + mloc) * 128;
  const int k0base = ks * 2048;

  f32x4 acc[4][4] = {};

  // staging: 4 GLD16 each; round i: row = i*32 + (tid>>3), chunk = tid&7
  const int sr = tid >> 3, sc = tid & 7;
  const unsigned short* asrc = xb + (size_t)m0 * DM + k0base;
  const unsigned short* bsrc = wb + (size_t)(ns * 128) * DM + k0base;

#pragma unroll 1
  for (int t = 0; t < 32; ++t) {
    const int k0 = t * 64;
    __syncthreads();   // readers done with previous tile
#pragma unroll
    for (int i = 0; i < 4; ++i) {
      int row = i * 32 + sr;
      GLD16(asrc + (size_t)row * DM + k0 + ((sc ^ (row & 7)) * 8),
            (char*)Alds + (i * 256 + tid) * 16);
    }
#pragma unroll
    for (int i = 0; i < 4; ++i) {
      int row = i * 32 + sr;
      GLD16(bsrc + (size_t)row * DM + k0 + ((sc ^ (row & 7)) * 8),
            (char*)Blds + (i * 256 + tid) * 16);
    }
    __syncthreads();   // drains the 8 GLD16: tile ready
#pragma unroll
    for (int kc = 0; kc < 2; ++kc) {
      short8 af[4], bf4[4];
#pragma unroll
      for (int mi = 0; mi < 4; ++mi) {
        int r = wm * 64 + mi * 16 + l15;
        af[mi] = *(short8*)&Alds[r * 64 + ((kc * 32 + lg * 8) ^ ((r & 7) << 3))];
      }
#pragma unroll
      for (int ni = 0; ni < 4; ++ni) {
        int r = wn * 64 + ni * 16 + l15;
        bf4[ni] = *(short8*)&Blds[r * 64 + ((kc * 32 + lg * 8) ^ ((r & 7) << 3))];
      }
#pragma unroll
      for (int mi = 0; mi < 4; ++mi)
#pragma unroll
        for (int ni = 0; ni < 4; ++ni)
          acc[mi][ni] = __builtin_amdgcn_mfma_f32_16x16x32_bf16(af[mi], bf4[ni], acc[mi][ni], 0, 0, 0);
    }
  }

  // store f32 partials
#pragma unroll
  for (int mi = 0; mi < 4; ++mi)
#pragma unroll
    for (int ni = 0; ni < 4; ++ni)
#pragma unroll
      for (int j2 = 0; j2 < 4; ++j2) {
        int r = wm * 64 + mi * 16 + lg * 4 + j2;
        int c = wn * 64 + ni * 16 + l15;
        pbuf[((size_t)ks * (SQ * NB) + m0 + r) * 384 + ns * 128 + c] = acc[mi][ni][j2];
      }
}

// ---------------- kernel 2A': reduce partials + bias + RoPE -> bf16 ----------------
__global__ __launch_bounds__(256) void reduce_qkv(
    const float* __restrict__ pbuf, const float* __restrict__ biasws,
    const float* __restrict__ sing, const float* __restrict__ cosg,
    unsigned short* __restrict__ qb, unsigned short* __restrict__ kb,
    unsigned short* __restrict__ vb) {
  const size_t idx0 = ((size_t)blockIdx.x * 256 + threadIdx.x) * 8;
  const int row = (int)(idx0 / 384);
  const int c = (int)(idx0 - (size_t)row * 384);   // multiple of 8; within one head
  const int head = c >> 7, h = c & 127;
  const float* P0 = pbuf + idx0;
  const float* P1 = pbuf + (size_t)SQ * NB * 384 + idx0;
  float4 a0 = *(const float4*)(P0), a1 = *(const float4*)(P0 + 4);
  float4 b0 = *(const float4*)(P1), b1 = *(const float4*)(P1 + 4);
  float4 bias0 = *(const float4*)(biasws + c), bias1 = *(const float4*)(biasws + c + 4);
  float v[8];
  v[0] = a0.x + b0.x + bias0.x; v[1] = a0.y + b0.y + bias0.y;
  v[2] = a0.z + b0.z + bias0.z; v[3] = a0.w + b0.w + bias0.w;
  v[4] = a1.x + b1.x + bias1.x; v[5] = a1.y + b1.y + bias1.y;
  v[6] = a1.z + b1.z + bias1.z; v[7] = a1.w + b1.w + bias1.w;
  if (head < 2) {
    // reference RoPE: out[h]=v[h]*cos[h]+v_sw[h]*sin[h], v_sw pair-local
    int s = row & (SQ - 1);
    const float* cp = cosg + (size_t)s * DH + h;
    const float* sp = sing + (size_t)s * DH + h;
    float4 c0 = *(const float4*)(cp), c1 = *(const float4*)(cp + 4);
    float4 s0 = *(const float4*)(sp), s1 = *(const float4*)(sp + 4);
    float cc[8] = {c0.x, c0.y, c0.z, c0.w, c1.x, c1.y, c1.z, c1.w};
    float ss[8] = {s0.x, s0.y, s0.z, s0.w, s1.x, s1.y, s1.z, s1.w};
    float o[8];
#pragma unroll
    for (int i = 0; i < 4; ++i) {
      float odd = v[2 * i + 1];
      o[2 * i]     = v[2 * i] * cc[2 * i] + odd * ss[2 * i];
      o[2 * i + 1] = odd * cc[2 * i + 1] + odd * ss[2 * i + 1];
    }
#pragma unroll
    for (int i = 0; i < 8; ++i) v[i] = o[i];
  }
  short8 o8;
#pragma unroll
  for (int i = 0; i < 8; ++i) o8[i] = (short)f2bf(v[i]);
  unsigned short* dst = (head == 0) ? qb : (head == 1) ? kb : vb;
  *(short8*)(dst + (size_t)row * DH + h) = o8;
}

// ---------------- kernel 2B (fallback if ws too small): R8 fused GEMM ----------------
__global__ __launch_bounds__(256) void gemm_qkv_rope_fused(
    const float* __restrict__ x, const unsigned short* __restrict__ wb,
    const float* __restrict__ biasws, const float* __restrict__ sing,
    const float* __restrict__ cosg, unsigned short* __restrict__ qb,
    unsigned short* __restrict__ kb, unsigned short* __restrict__ vb) {
  __shared__ __align__(16) short Alds[2 * 64 * 64];
  __shared__ __align__(16) short Blds[2 * 128 * 64];
  const int tid = threadIdx.x;
  const int l = tid & 63, w = tid >> 6;
  const int wm = w >> 1, wn = w & 1;
  const int l15 = l & 15, lg = l >> 4;
  const int bid = blockIdx.x;
  const int xcd = bid & 7, j = bid >> 3;
  const int mloc = j / 3, head = j - mloc * 3;
  const int m0 = (xcd * 32 + mloc) * 64;
  f32x4 acc[2][4] = {};
  const int ar0 = tid >> 4, ac4 = (tid & 15) * 4;
  const float* xsrc = x + (size_t)(m0 + ar0) * DM + ac4;
  const int achunk = (tid & 15) >> 1, ahalf = tid & 1;
  const int brow_ = tid >> 3, bchunk = tid & 7;
  const unsigned short* wbh = wb + (size_t)head * 128 * DM;
  float4 a00, a01, a02, a03, a10, a11, a12, a13;
  {
#pragma unroll
    for (int i = 0; i < 4; ++i) {
      float4 f = *(const float4*)(xsrc + (size_t)i * 16 * DM);
      int row = ar0 + i * 16;
      *(uint2*)&Alds[row * 64 + ((achunk ^ (row & 7)) * 8) + ahalf * 4] = cvt4(f);
    }
#pragma unroll
    for (int i = 0; i < 4; ++i) {
      int row = i * 32 + brow_;
      int slot = i * 256 + tid;
      GLD16(wbh + (size_t)row * DM + ((bchunk ^ (row & 7)) * 8), (char*)Blds + slot * 16);
    }
    a00 = *(const float4*)(xsrc + 64);
    a01 = *(const float4*)(xsrc + (size_t)16 * DM + 64);
    a02 = *(const float4*)(xsrc + (size_t)32 * DM + 64);
    a03 = *(const float4*)(xsrc + (size_t)48 * DM + 64);
  }
  auto giter = [&](int t, int CUR,
                   float4& n0, float4& n1, float4& n2, float4& n3,
                   float4& f0, float4& f1, float4& f2, float4& f3) {
    asm volatile("s_waitcnt vmcnt(4) lgkmcnt(0)" ::: "memory");
    __builtin_amdgcn_sched_barrier(0);
    __builtin_amdgcn_s_barrier();
    __builtin_amdgcn_sched_barrier(0);
    const int kB = (t + 1) * 64;
    char* bdst = (char*)Blds + (CUR ^ 1) * 16384;
#pragma unroll
    for (int i = 0; i < 4; ++i) {
      int row = i * 32 + brow_;
      int slot = i * 256 + tid;
      GLD16(wbh + (size_t)row * DM + kB + ((bchunk ^ (row & 7)) * 8), bdst + slot * 16);
    }
    __builtin_amdgcn_sched_barrier(0);
    const int kF = (t < 62) ? (t + 2) * 64 : 0;
    f0 = *(const float4*)(xsrc + kF);
    f1 = *(const float4*)(xsrc + (size_t)16 * DM + kF);
    f2 = *(const float4*)(xsrc + (size_t)32 * DM + kF);
    f3 = *(const float4*)(xsrc + (size_t)48 * DM + kF);
#pragma unroll
    for (int kc = 0; kc < 2; ++kc) {
      short8 af[2], bfr[4];
#pragma unroll
      for (int mi = 0; mi < 2; ++mi) {
        int r = wm * 32 + mi * 16 + l15;
        af[mi] = *(short8*)&Alds[CUR * 4096 + r * 64 + ((kc * 32 + lg * 8) ^ ((r & 7) << 3))];
      }
#pragma unroll
      for (int ni = 0; ni < 4; ++ni) {
        int r = wn * 64 + ni * 16 + l15;
        bfr[ni] = *(short8*)&Blds[CUR * 8192 + r * 64 + ((kc * 32 + lg * 8) ^ ((r & 7) << 3))];
      }
#pragma unroll
      for (int mi = 0; mi < 2; ++mi)
#pragma unroll
        for (int ni = 0; ni < 4; ++ni)
          acc[mi][ni] = __builtin_amdgcn_mfma_f32_16x16x32_bf16(af[mi], bfr[ni], acc[mi][ni], 0, 0, 0);
    }
    short* Adst = &Alds[(CUR ^ 1) * 4096];
    int r0 = ar0, r1 = ar0 + 16, r2 = ar0 + 32, r3 = ar0 + 48;
    *(uint2*)&Adst[r0 * 64 + ((achunk ^ (r0 & 7)) * 8) + ahalf * 4] = cvt4(n0);
    *(uint2*)&Adst[r1 * 64 + ((achunk ^ (r1 & 7)) * 8) + ahalf * 4] = cvt4(n1);
    *(uint2*)&Adst[r2 * 64 + ((achunk ^ (r2 & 7)) * 8) + ahalf * 4] = cvt4(n2);
    *(uint2*)&Adst[r3 * 64 + ((achunk ^ (r3 & 7)) * 8) + ahalf * 4] = cvt4(n3);
  };
#pragma unroll 1
  for (int t = 0; t < 62; t += 2) {
    giter(t, 0, a00, a01, a02, a03, a10, a11, a12, a13);
    giter(t + 1, 1, a10, a11, a12, a13, a00, a01, a02, a03);
  }
  giter(62, 0, a00, a01, a02, a03, a10, a11, a12, a13);
  {
    asm volatile("s_waitcnt vmcnt(0) lgkmcnt(0)" ::: "memory");
    __builtin_amdgcn_sched_barrier(0);
    __builtin_amdgcn_s_barrier();
    __builtin_amdgcn_sched_barrier(0);
#pragma unroll
    for (int kc = 0; kc < 2; ++kc) {
      short8 af[2], bfr[4];
#pragma unroll
      for (int mi = 0; mi < 2; ++mi) {
        int r = wm * 32 + mi * 16 + l15;
        af[mi] = *(short8*)&Alds[4096 + r * 64 + ((kc * 32 + lg * 8) ^ ((r & 7) << 3))];
      }
#pragma unroll
      for (int ni = 0; ni < 4; ++ni) {
        int r = wn * 64 + ni * 16 + l15;
        bfr[ni] = *(short8*)&Blds[8192 + r * 64 + ((kc * 32 + lg * 8) ^ ((r & 7) << 3))];
      }
#pragma unroll
      for (int mi = 0; mi < 2; ++mi)
#pragma unroll
        for (int ni = 0; ni < 4; ++ni)
          acc[mi][ni] = __builtin_amdgcn_mfma_f32_16x16x32_bf16(af[mi], bfr[ni], acc[mi][ni], 0, 0, 0);
    }
  }
  unsigned short* dst = (head == 0) ? qb : (head == 1) ? kb : vb;
#pragma unroll
  for (int mi = 0; mi < 2; ++mi)
#pragma unroll
    for (int ni = 0; ni < 4; ++ni) {
      int h = wn * 64 + ni * 16 + l15;
      float bias = biasws[head * 128 + h];
      f32x4 a = acc[mi][ni];
#pragma unroll
      for (int j2 = 0; j2 < 4; ++j2) {
        int row = m0 + wm * 32 + mi * 16 + lg * 4 + j2;
        float val = a[j2] + bias;
        if (head < 2) {
          int s = row & (SQ - 1);
          float cs = cosg[s * DH + h];
          float sn = sing[s * DH + h];
          float pr = __shfl_xor(val, 1, 64);
          float sw = (l & 1) ? val : pr;
          val = val * cs + sw * sn;
        }
        dst[(size_t)row * DH + h] = f2bf(val);
      }
    }
}

// ---------------- kernel 2b: V -> V^T (per batch [128][4096]) ----------------
__global__ __launch_bounds__(256) void transpose_v(const unsigned short* __restrict__ vb,
                                                   unsigned short* __restrict__ vt) {
  __shared__ short T[128 * 72];
  const int b = blockIdx.x >> 6;
  const int s0 = (blockIdx.x & 63) * 64;
  const int t = threadIdx.x;
  {
    const int sl = t >> 2, dc = (t & 3) * 32;
    const unsigned short* src = vb + ((size_t)b * SQ + s0 + sl) * DH + dc;
#pragma unroll
    for (int i = 0; i < 4; ++i) {
      short8 v = *(const short8*)(src + i * 8);
#pragma unroll
      for (int j = 0; j < 8; ++j) T[(dc + i * 8 + j) * 72 + sl] = v[j];
    }
  }
  __syncthreads();
  {
    const int d = t >> 1, sh = (t & 1) * 32;
    unsigned short* dst = vt + ((size_t)b * DH + d) * SQ + s0 + sh;
#pragma unroll
    for (int i = 0; i < 4; ++i) {
      short8 w;
#pragma unroll
      for (int j = 0; j < 8; ++j) w[j] = T[d * 72 + sh + i * 8 + j];
      *(short8*)(dst + i * 8) = w;
    }
  }
}

// ---------------- kernel 3: causal flash attention ----------------
__global__ __launch_bounds__(256) void attn_kernel(
    const unsigned short* __restrict__ qb, const unsigned short* __restrict__ kb,
    const unsigned short* __restrict__ vt, float* __restrict__ out) {
  __shared__ __align__(16) float Obuf[3 * 16 * 132];
  __shared__ __align__(16) float Mlds[64];
  __shared__ __align__(16) float Llds[64];
  __shared__ __align__(16) float Clds[64];
  const int tid = threadIdx.x;
  const int w = tid >> 6, l = tid & 63;
  const int l15 = l & 15, lg = l >> 4;
  const int bi = blockIdx.x;
  const int slot = bi & 7, p = slot & 1, batch = slot >> 1;
  const int idx = bi >> 3, ci = idx & 31, r = idx >> 5;
  const int a = ci + 32 * p;
  const int qt = (r == 0) ? a : (r == 1) ? 255 - a : (r == 2) ? 128 + a : 127 - a;
  const int q0 = qt * 16;
  const size_t bbase = (size_t)batch * SQ;
  const unsigned short* Kb = kb + bbase * DH;
  const unsigned short* Vt = vt + (size_t)batch * DH * SQ;
  short* Pw = (short*)Obuf + w * 1152;
  short8 qf[4];
  {
    const unsigned short* qp = qb + (bbase + q0 + l15) * DH + lg * 8;
#pragma unroll
    for (int kcd = 0; kcd < 4; ++kcd) qf[kcd] = *(const short8*)(qp + kcd * 32);
  }
  float m_r = -INFINITY, l_r = 0.f;
  f32x4 o[8] = {};
  const int nsteps = qt / 4 + 1;
  for (int st = w; st < nsteps; st += 4) {
    const int kv0 = st * 64;
    short8 kf[4][4];
#pragma unroll
    for (int ni = 0; ni < 4; ++ni) {
      const unsigned short* kp = Kb + (size_t)(kv0 + ni * 16 + l15) * DH + lg * 8;
#pragma unroll
      for (int kcd = 0; kcd < 4; ++kcd) kf[ni][kcd] = *(const short8*)(kp + kcd * 32);
    }
    f32x4 sf[4] = {};
    __builtin_amdgcn_s_setprio(1);
#pragma unroll
    for (int kcd = 0; kcd < 4; ++kcd)
#pragma unroll
      for (int ni = 0; ni < 4; ++ni)
        sf[ni] = __builtin_amdgcn_mfma_f32_16x16x32_bf16(kf[ni][kcd], qf[kcd], sf[ni], 0, 0, 0);
    __builtin_amdgcn_s_setprio(0);
    short8 vf[8][2];
#pragma unroll
    for (int nd = 0; nd < 8; ++nd) {
      const unsigned short* vp = Vt + (size_t)(nd * 16 + l15) * SQ + kv0 + lg * 8;
      vf[nd][0] = *(const short8*)(vp);
      vf[nd][1] = *(const short8*)(vp + 32);
    }
    float s[4][4];
    if (st == nsteps - 1) {
#pragma unroll
      for (int ni = 0; ni < 4; ++ni)
#pragma unroll
        for (int j = 0; j < 4; ++j) {
          float v = sf[ni][j] * SCL2;
          if (kv0 + ni * 16 + lg * 4 + j > q0 + l15) v = -FLT_MAX;
          s[ni][j] = v;
        }
    } else {
#pragma unroll
      for (int ni = 0; ni < 4; ++ni)
#pragma unroll
        for (int j = 0; j < 4; ++j) s[ni][j] = sf[ni][j] * SCL2;
    }
    float tmx = s[0][0];
#pragma unroll
    for (int ni = 0; ni < 4; ++ni)
#pragma unroll
      for (int j = 0; j < 4; ++j) tmx = fmaxf(tmx, s[ni][j]);
    tmx = fmaxf(tmx, __shfl_xor(tmx, 16, 64));
    tmx = fmaxf(tmx, __shfl_xor(tmx, 32, 64));
    if (__any(tmx > m_r + 8.0f)) {
      float mnew = fmaxf(m_r, tmx);
      float corr = exp2f(m_r - mnew);
      if (l < 16) Clds[w * 16 + l] = corr;
      l_r *= corr; m_r = mnew;
      f32x4 c4 = *(f32x4*)&Clds[w * 16 + lg * 4];
#pragma unroll
      for (int nd = 0; nd < 8; ++nd)
#pragma unroll
        for (int j = 0; j < 4; ++j) o[nd][j] *= c4[j];
    }
    float rs = 0.f;
    float pp[4][4];
#pragma unroll
    for (int ni = 0; ni < 4; ++ni)
#pragma unroll
      for (int j = 0; j < 4; ++j) {
        pp[ni][j] = exp2f(s[ni][j] - m_r);
        rs += pp[ni][j];
      }
    rs += __shfl_xor(rs, 16, 64);
    rs += __shfl_xor(rs, 32, 64);
    l_r += rs;
#pragma unroll
    for (int ni = 0; ni < 4; ++ni) {
      uint32 lo, hi;
      asm volatile("v_cvt_pk_bf16_f32 %0, %1, %2" : "=v"(lo) : "v"(pp[ni][0]), "v"(pp[ni][1]));
      asm volatile("v_cvt_pk_bf16_f32 %0, %1, %2" : "=v"(hi) : "v"(pp[ni][2]), "v"(pp[ni][3]));
      uint2 u; u.x = lo; u.y = hi;
      *(uint2*)&Pw[l15 * 72 + ni * 16 + lg * 4] = u;
    }
    short8 pa0 = *(short8*)&Pw[l15 * 72 + lg * 8];
    short8 pa1 = *(short8*)&Pw[l15 * 72 + 32 + lg * 8];
    __builtin_amdgcn_s_setprio(1);
#pragma unroll
    for (int nd = 0; nd < 8; ++nd) {
      o[nd] = __builtin_amdgcn_mfma_f32_16x16x32_bf16(pa0, vf[nd][0], o[nd], 0, 0, 0);
      o[nd] = __builtin_amdgcn_mfma_f32_16x16x32_bf16(pa1, vf[nd][1], o[nd], 0, 0, 0);
    }
    __builtin_amdgcn_s_setprio(0);
  }
  if (l < 16) { Mlds[w * 16 + l] = m_r; Llds[w * 16 + l] = l_r; }
  __syncthreads();
  if (w > 0) {
#pragma unroll
    for (int nd = 0; nd < 8; ++nd)
#pragma unroll
      for (int j = 0; j < 4; ++j)
        Obuf[(w - 1) * 2112 + (lg * 4 + j) * 132 + nd * 16 + l15] = o[nd][j];
  }
  __syncthreads();
  if (w == 0) {
    float al[4][4], Lt[4];
#pragma unroll
    for (int j = 0; j < 4; ++j) {
      int q = lg * 4 + j;
      float M = Mlds[q];
#pragma unroll
      for (int ww = 1; ww < 4; ++ww) M = fmaxf(M, Mlds[ww * 16 + q]);
      float sL = 0.f;
#pragma unroll
      for (int ww = 0; ww < 4; ++ww) {
        float aa = exp2f(Mlds[ww * 16 + q] - M);
        al[ww][j] = aa; sL += aa * Llds[ww * 16 + q];
      }
      Lt[j] = sL;
    }
#pragma unroll
    for (int nd = 0; nd < 8; ++nd)
#pragma unroll
      for (int j = 0; j < 4; ++j) {
        float acc2 = al[0][j] * o[nd][j];
#pragma unroll
        for (int ww = 1; ww < 4; ++ww)
          acc2 += al[ww][j] * Obuf[(ww - 1) * 2112 + (lg * 4 + j) * 132 + nd * 16 + l15];
        out[(bbase + q0 + lg * 4 + j) * DH + nd * 16 + l15] = acc2 / Lt[j];
      }
  }
}

extern "C" void kernel_launch(void* const* d_in, const int* in_sizes, int n_in,
                              void* d_out, int out_size, void* d_ws, size_t ws_size,
                              hipStream_t stream) {
  const float* x    = (const float*)d_in[0];
  const float* wq   = (const float*)d_in[1];
  const float* bq   = (const float*)d_in[2];
  const float* wk   = (const float*)d_in[3];
  const float* bk   = (const float*)d_in[4];
  const float* wv   = (const float*)d_in[5];
  const float* bv   = (const float*)d_in[6];
  const float* sing = (const float*)d_in[7];
  const float* cosg = (const float*)d_in[8];
  float* out = (float*)d_out;

  char* ws = (char*)d_ws;
  unsigned short* wb = (unsigned short*)ws;                        // 3,145,728 B
  float* biasws = (float*)(ws + 3145728);                          // 1,536 B
  unsigned short* qb = (unsigned short*)(ws + 3147264);            // 4 MB
  unsigned short* kb = (unsigned short*)(ws + 3147264 + 4194304);  // 4 MB
  unsigned short* vb = (unsigned short*)(ws + 3147264 + 2 * 4194304);  // 4 MB
  unsigned short* vt = (unsigned short*)(ws + 3147264 + 3 * 4194304);  // 4 MB
  float* pbuf = (float*)(ws + 19924480);                           // 50,331,648 B
  unsigned short* xbuf = (unsigned short*)(ws + 70256128);         // 134,217,728 B
  const size_t WS_NEED = 70256128ull + 134217728ull;               // 204,473,856

  cast_w_kernel<<<768, 256, 0, stream>>>(wq, wk, wv, bq, bk, bv, wb, biasws);
  if (ws_size >= WS_NEED) {
    cast_x_kernel<<<2048, 256, 0, stream>>>(x, xbuf);
    gemm_qkv_split<<<768, 256, 0, stream>>>(xbuf, wb, pbuf);
    reduce_qkv<<<3072, 256, 0, stream>>>(pbuf, biasws, sing, cosg, qb, kb, vb);
  } else {
    gemm_qkv_rope_fused<<<768, 256, 0, stream>>>(x, wb, biasws, sing, cosg, qb, kb, vb);
  }
  transpose_v<<<256, 256, 0, stream>>>(vb, vt);
  attn_kernel<<<1024, 256, 0, stream>>>(qb, kb, vt, out);
}

// Round 13
// 227.708 us; speedup vs baseline: 1.2785x; 1.2785x over previous
//
#include <hip/hip_runtime.h>
#include <hip/hip_bf16.h>
#include <float.h>
#include <math.h>

typedef float f32x4 __attribute__((ext_vector_type(4)));
typedef short short8 __attribute__((ext_vector_type(8)));
typedef unsigned int uint32;

#define NB 4
#define SQ 4096
#define DM 4096
#define DH 128
#define LOG2E 1.44269504088896f
#define SCALE 0.0883883476483184f   // 1/sqrt(128)
#define SCL2 (SCALE * LOG2E)        // fold into log2 domain

__device__ __forceinline__ unsigned short f2bf(float f) {
  union { float f; unsigned u; } x; x.f = f;
  unsigned r = x.u + 0x7FFFu + ((x.u >> 16) & 1u);
  return (unsigned short)(r >> 16);
}

__device__ __forceinline__ uint2 cvt4(float4 f) {
  uint2 u;
  asm("v_cvt_pk_bf16_f32 %0, %1, %2" : "=v"(u.x) : "v"(f.x), "v"(f.y));
  asm("v_cvt_pk_bf16_f32 %0, %1, %2" : "=v"(u.y) : "v"(f.z), "v"(f.w));
  return u;
}

#define GLD16(g, l) __builtin_amdgcn_global_load_lds( \
    (const __attribute__((address_space(1))) void*)(g), \
    (__attribute__((address_space(3))) void*)(l), 16, 0, 0)

// ---------------- kernel 1: pack weights (bf16) + bias (f32) ----------------
__global__ void cast_w_kernel(const float* __restrict__ wq, const float* __restrict__ wk,
                              const float* __restrict__ wv, const float* __restrict__ bq,
                              const float* __restrict__ bk, const float* __restrict__ bv,
                              unsigned short* __restrict__ wb, float* __restrict__ biasws) {
  int t = blockIdx.x * 256 + threadIdx.x;  // 0..196607, each handles 8 elems
  int base = t * 8;
  int n = base >> 12;       // output row 0..383 (q:0-127, k:128-255, v:256-383)
  int d = base & 4095;
  const float* src = (n < 128) ? (wq + (size_t)n * DM)
                   : (n < 256) ? (wk + (size_t)(n - 128) * DM)
                               : (wv + (size_t)(n - 256) * DM);
  float4 f0 = *(const float4*)(src + d);
  float4 f1 = *(const float4*)(src + d + 4);
  short8 v;
  v[0] = (short)f2bf(f0.x); v[1] = (short)f2bf(f0.y);
  v[2] = (short)f2bf(f0.z); v[3] = (short)f2bf(f0.w);
  v[4] = (short)f2bf(f1.x); v[5] = (short)f2bf(f1.y);
  v[6] = (short)f2bf(f1.z); v[7] = (short)f2bf(f1.w);
  *(short8*)(wb + base) = v;
  if (t < 384) biasws[t] = (t < 128) ? bq[t] : (t < 256) ? bk[t - 128] : bv[t - 256];
}

// ---------------- kernel 2: fused QKV GEMM + bias + RoPE (+ V^T store) ------
// R8 structure (best measured: 150 us): BM=64, BN=128 (one head per block),
// BK=64, 4 waves (2m x 2n), 3 blocks/CU, counted-vmcnt pipeline, one raw
// s_barrier/iter. NEW: for head==2 the epilogue writes V TRANSPOSED directly
// (vt[h][s], 8B packed stores of 4 consecutive s) -- transpose_v kernel gone.
__global__ __launch_bounds__(256) void gemm_qkv_rope(
    const float* __restrict__ x, const unsigned short* __restrict__ wb,
    const float* __restrict__ biasws, const float* __restrict__ sing,
    const float* __restrict__ cosg, unsigned short* __restrict__ qb,
    unsigned short* __restrict__ kb, unsigned short* __restrict__ vt) {
  __shared__ __align__(16) short Alds[2 * 64 * 64];
  __shared__ __align__(16) short Blds[2 * 128 * 64];
  const int tid = threadIdx.x;
  const int l = tid & 63, w = tid >> 6;
  const int wm = w >> 1, wn = w & 1;
  const int l15 = l & 15, lg = l >> 4;
  const int bid = blockIdx.x;
  const int xcd = bid & 7, j = bid >> 3;
  const int mloc = j / 3, head = j - mloc * 3;
  const int m0 = (xcd * 32 + mloc) * 64;
  f32x4 acc[2][4] = {};
  const int ar0 = tid >> 4, ac4 = (tid & 15) * 4;
  const float* xsrc = x + (size_t)(m0 + ar0) * DM + ac4;
  const int achunk = (tid & 15) >> 1, ahalf = tid & 1;
  const int brow_ = tid >> 3, bchunk = tid & 7;
  const unsigned short* wbh = wb + (size_t)head * 128 * DM;
  float4 a00, a01, a02, a03, a10, a11, a12, a13;
  {
#pragma unroll
    for (int i = 0; i < 4; ++i) {
      float4 f = *(const float4*)(xsrc + (size_t)i * 16 * DM);
      int row = ar0 + i * 16;
      *(uint2*)&Alds[row * 64 + ((achunk ^ (row & 7)) * 8) + ahalf * 4] = cvt4(f);
    }
#pragma unroll
    for (int i = 0; i < 4; ++i) {
      int row = i * 32 + brow_;
      int slot = i * 256 + tid;
      GLD16(wbh + (size_t)row * DM + ((bchunk ^ (row & 7)) * 8), (char*)Blds + slot * 16);
    }
    a00 = *(const float4*)(xsrc + 64);
    a01 = *(const float4*)(xsrc + (size_t)16 * DM + 64);
    a02 = *(const float4*)(xsrc + (size_t)32 * DM + 64);
    a03 = *(const float4*)(xsrc + (size_t)48 * DM + 64);
  }
  auto giter = [&](int t, int CUR,
                   float4& n0, float4& n1, float4& n2, float4& n3,
                   float4& f0, float4& f1, float4& f2, float4& f3) {
    asm volatile("s_waitcnt vmcnt(4) lgkmcnt(0)" ::: "memory");
    __builtin_amdgcn_sched_barrier(0);
    __builtin_amdgcn_s_barrier();
    __builtin_amdgcn_sched_barrier(0);
    const int kB = (t + 1) * 64;
    char* bdst = (char*)Blds + (CUR ^ 1) * 16384;
#pragma unroll
    for (int i = 0; i < 4; ++i) {
      int row = i * 32 + brow_;
      int slot = i * 256 + tid;
      GLD16(wbh + (size_t)row * DM + kB + ((bchunk ^ (row & 7)) * 8), bdst + slot * 16);
    }
    __builtin_amdgcn_sched_barrier(0);
    const int kF = (t < 62) ? (t + 2) * 64 : 0;
    f0 = *(const float4*)(xsrc + kF);
    f1 = *(const float4*)(xsrc + (size_t)16 * DM + kF);
    f2 = *(const float4*)(xsrc + (size_t)32 * DM + kF);
    f3 = *(const float4*)(xsrc + (size_t)48 * DM + kF);
#pragma unroll
    for (int kc = 0; kc < 2; ++kc) {
      short8 af[2], bfr[4];
#pragma unroll
      for (int mi = 0; mi < 2; ++mi) {
        int r = wm * 32 + mi * 16 + l15;
        af[mi] = *(short8*)&Alds[CUR * 4096 + r * 64 + ((kc * 32 + lg * 8) ^ ((r & 7) << 3))];
      }
#pragma unroll
      for (int ni = 0; ni < 4; ++ni) {
        int r = wn * 64 + ni * 16 + l15;
        bfr[ni] = *(short8*)&Blds[CUR * 8192 + r * 64 + ((kc * 32 + lg * 8) ^ ((r & 7) << 3))];
      }
#pragma unroll
      for (int mi = 0; mi < 2; ++mi)
#pragma unroll
        for (int ni = 0; ni < 4; ++ni)
          acc[mi][ni] = __builtin_amdgcn_mfma_f32_16x16x32_bf16(af[mi], bfr[ni], acc[mi][ni], 0, 0, 0);
    }
    short* Adst = &Alds[(CUR ^ 1) * 4096];
    int r0 = ar0, r1 = ar0 + 16, r2 = ar0 + 32, r3 = ar0 + 48;
    *(uint2*)&Adst[r0 * 64 + ((achunk ^ (r0 & 7)) * 8) + ahalf * 4] = cvt4(n0);
    *(uint2*)&Adst[r1 * 64 + ((achunk ^ (r1 & 7)) * 8) + ahalf * 4] = cvt4(n1);
    *(uint2*)&Adst[r2 * 64 + ((achunk ^ (r2 & 7)) * 8) + ahalf * 4] = cvt4(n2);
    *(uint2*)&Adst[r3 * 64 + ((achunk ^ (r3 & 7)) * 8) + ahalf * 4] = cvt4(n3);
  };
#pragma unroll 1
  for (int t = 0; t < 62; t += 2) {
    giter(t, 0, a00, a01, a02, a03, a10, a11, a12, a13);
    giter(t + 1, 1, a10, a11, a12, a13, a00, a01, a02, a03);
  }
  giter(62, 0, a00, a01, a02, a03, a10, a11, a12, a13);
  {
    asm volatile("s_waitcnt vmcnt(0) lgkmcnt(0)" ::: "memory");
    __builtin_amdgcn_sched_barrier(0);
    __builtin_amdgcn_s_barrier();
    __builtin_amdgcn_sched_barrier(0);
#pragma unroll
    for (int kc = 0; kc < 2; ++kc) {
      short8 af[2], bfr[4];
#pragma unroll
      for (int mi = 0; mi < 2; ++mi) {
        int r = wm * 32 + mi * 16 + l15;
        af[mi] = *(short8*)&Alds[4096 + r * 64 + ((kc * 32 + lg * 8) ^ ((r & 7) << 3))];
      }
#pragma unroll
      for (int ni = 0; ni < 4; ++ni) {
        int r = wn * 64 + ni * 16 + l15;
        bfr[ni] = *(short8*)&Blds[8192 + r * 64 + ((kc * 32 + lg * 8) ^ ((r & 7) << 3))];
      }
#pragma unroll
      for (int mi = 0; mi < 2; ++mi)
#pragma unroll
        for (int ni = 0; ni < 4; ++ni)
          acc[mi][ni] = __builtin_amdgcn_mfma_f32_16x16x32_bf16(af[mi], bfr[ni], acc[mi][ni], 0, 0, 0);
    }
  }
  if (head == 2) {
    // V: write TRANSPOSED directly. acc frag holds 4 consecutive seq-rows for
    // one h -> single 8B store into vt[batch][h][s0..s0+3]. A block covers 64
    // contiguous s for every h -> L2 write-combines to 128B spans per h.
    unsigned short* vtb = vt + (size_t)(m0 >> 12) * DH * SQ;
    const int srow = (m0 & (SQ - 1)) + wm * 32;
#pragma unroll
    for (int mi = 0; mi < 2; ++mi)
#pragma unroll
      for (int ni = 0; ni < 4; ++ni) {
        int h = wn * 64 + ni * 16 + l15;
        float bias = biasws[256 + h];
        f32x4 a = acc[mi][ni];
        float4 f;
        f.x = a[0] + bias; f.y = a[1] + bias; f.z = a[2] + bias; f.w = a[3] + bias;
        *(uint2*)&vtb[(size_t)h * SQ + srow + mi * 16 + lg * 4] = cvt4(f);
      }
  } else {
    unsigned short* dst = (head == 0) ? qb : kb;
#pragma unroll
    for (int mi = 0; mi < 2; ++mi)
#pragma unroll
      for (int ni = 0; ni < 4; ++ni) {
        int h = wn * 64 + ni * 16 + l15;
        float bias = biasws[head * 128 + h];
        f32x4 a = acc[mi][ni];
#pragma unroll
        for (int j2 = 0; j2 < 4; ++j2) {
          int row = m0 + wm * 32 + mi * 16 + lg * 4 + j2;
          float val = a[j2] + bias;
          // reference RoPE: out[h] = v[h]*cos[h] + v_sw[h]*sin[h],
          // v_sw[2i] = v_sw[2i+1] = v[2i+1] (odd element, repeated)
          int s = row & (SQ - 1);
          float cs = cosg[s * DH + h];
          float sn = sing[s * DH + h];
          float pr = __shfl_xor(val, 1, 64);      // partner col h^1 (same row)
          float sw = (l & 1) ? val : pr;          // odd h: self; even h: h+1
          val = val * cs + sw * sn;
          dst[(size_t)row * DH + h] = f2bf(val);
        }
      }
  }
}

// ---------------- kernel 3: causal flash attention ----------------
// 4 waves/block, one 16-row q-tile per block, KV steps strided across waves
// (flash-decoding split). Swapped QK^T (S^T = K*Q): softmax in-lane over 16 +
// 2 shuffles. Log2-domain scores. Defer-max (THR=8). Merge parallelized:
// every wave combines 2 of the 8 d-slices (was: wave 0 did all 32 stores).
__global__ __launch_bounds__(256) void attn_kernel(
    const unsigned short* __restrict__ qb, const unsigned short* __restrict__ kb,
    const unsigned short* __restrict__ vt, float* __restrict__ out) {
  __shared__ __align__(16) float Obuf[4 * 16 * 132];  // 33792 B; P staging aliases (synced)
  __shared__ __align__(16) float Mlds[64];
  __shared__ __align__(16) float Llds[64];
  __shared__ __align__(16) float Clds[64];
  const int tid = threadIdx.x;
  const int w = tid >> 6, l = tid & 63;
  const int l15 = l & 15, lg = l >> 4;
  const int bi = blockIdx.x;
  const int slot = bi & 7, p = slot & 1, batch = slot >> 1;
  const int idx = bi >> 3, ci = idx & 31, r = idx >> 5;
  const int a = ci + 32 * p;
  const int qt = (r == 0) ? a : (r == 1) ? 255 - a : (r == 2) ? 128 + a : 127 - a;
  const int q0 = qt * 16;
  const size_t bbase = (size_t)batch * SQ;
  const unsigned short* Kb = kb + bbase * DH;
  const unsigned short* Vt = vt + (size_t)batch * DH * SQ;
  short* Pw = (short*)Obuf + w * 1152;   // per-wave P staging [16][72] bf16
  short8 qf[4];
  {
    const unsigned short* qp = qb + (bbase + q0 + l15) * DH + lg * 8;
#pragma unroll
    for (int kcd = 0; kcd < 4; ++kcd) qf[kcd] = *(const short8*)(qp + kcd * 32);
  }
  float m_r = -INFINITY, l_r = 0.f;
  f32x4 o[8] = {};
  const int nsteps = qt / 4 + 1;
  for (int st = w; st < nsteps; st += 4) {
    const int kv0 = st * 64;
    short8 kf[4][4];
#pragma unroll
    for (int ni = 0; ni < 4; ++ni) {
      const unsigned short* kp = Kb + (size_t)(kv0 + ni * 16 + l15) * DH + lg * 8;
#pragma unroll
      for (int kcd = 0; kcd < 4; ++kcd) kf[ni][kcd] = *(const short8*)(kp + kcd * 32);
    }
    f32x4 sf[4] = {};
    __builtin_amdgcn_s_setprio(1);
#pragma unroll
    for (int kcd = 0; kcd < 4; ++kcd)
#pragma unroll
      for (int ni = 0; ni < 4; ++ni)
        sf[ni] = __builtin_amdgcn_mfma_f32_16x16x32_bf16(kf[ni][kcd], qf[kcd], sf[ni], 0, 0, 0);
    __builtin_amdgcn_s_setprio(0);
    short8 vf[8][2];
#pragma unroll
    for (int nd = 0; nd < 8; ++nd) {
      const unsigned short* vp = Vt + (size_t)(nd * 16 + l15) * SQ + kv0 + lg * 8;
      vf[nd][0] = *(const short8*)(vp);
      vf[nd][1] = *(const short8*)(vp + 32);
    }
    float s[4][4];
    if (st == nsteps - 1) {
#pragma unroll
      for (int ni = 0; ni < 4; ++ni)
#pragma unroll
        for (int j = 0; j < 4; ++j) {
          float v = sf[ni][j] * SCL2;
          if (kv0 + ni * 16 + lg * 4 + j > q0 + l15) v = -FLT_MAX;
          s[ni][j] = v;
        }
    } else {
#pragma unroll
      for (int ni = 0; ni < 4; ++ni)
#pragma unroll
        for (int j = 0; j < 4; ++j) s[ni][j] = sf[ni][j] * SCL2;
    }
    float tmx = s[0][0];
#pragma unroll
    for (int ni = 0; ni < 4; ++ni)
#pragma unroll
      for (int j = 0; j < 4; ++j) tmx = fmaxf(tmx, s[ni][j]);
    tmx = fmaxf(tmx, __shfl_xor(tmx, 16, 64));
    tmx = fmaxf(tmx, __shfl_xor(tmx, 32, 64));
    if (__any(tmx > m_r + 8.0f)) {
      float mnew = fmaxf(m_r, tmx);
      float corr = exp2f(m_r - mnew);
      if (l < 16) Clds[w * 16 + l] = corr;
      l_r *= corr; m_r = mnew;
      f32x4 c4 = *(f32x4*)&Clds[w * 16 + lg * 4];
#pragma unroll
      for (int nd = 0; nd < 8; ++nd)
#pragma unroll
        for (int j = 0; j < 4; ++j) o[nd][j] *= c4[j];
    }
    float rs = 0.f;
    float pp[4][4];
#pragma unroll
    for (int ni = 0; ni < 4; ++ni)
#pragma unroll
      for (int j = 0; j < 4; ++j) {
        pp[ni][j] = exp2f(s[ni][j] - m_r);
        rs += pp[ni][j];
      }
    rs += __shfl_xor(rs, 16, 64);
    rs += __shfl_xor(rs, 32, 64);
    l_r += rs;
#pragma unroll
    for (int ni = 0; ni < 4; ++ni) {
      uint32 lo, hi;
      asm volatile("v_cvt_pk_bf16_f32 %0, %1, %2" : "=v"(lo) : "v"(pp[ni][0]), "v"(pp[ni][1]));
      asm volatile("v_cvt_pk_bf16_f32 %0, %1, %2" : "=v"(hi) : "v"(pp[ni][2]), "v"(pp[ni][3]));
      uint2 u; u.x = lo; u.y = hi;
      *(uint2*)&Pw[l15 * 72 + ni * 16 + lg * 4] = u;
    }
    short8 pa0 = *(short8*)&Pw[l15 * 72 + lg * 8];
    short8 pa1 = *(short8*)&Pw[l15 * 72 + 32 + lg * 8];
    __builtin_amdgcn_s_setprio(1);
#pragma unroll
    for (int nd = 0; nd < 8; ++nd) {
      o[nd] = __builtin_amdgcn_mfma_f32_16x16x32_bf16(pa0, vf[nd][0], o[nd], 0, 0, 0);
      o[nd] = __builtin_amdgcn_mfma_f32_16x16x32_bf16(pa1, vf[nd][1], o[nd], 0, 0, 0);
    }
    __builtin_amdgcn_s_setprio(0);
  }
  // --- merge: all-wave parallel ---
  if (l < 16) { Mlds[w * 16 + l] = m_r; Llds[w * 16 + l] = l_r; }
  __syncthreads();   // ALL P-staging done (Obuf aliases P region); M/L visible
#pragma unroll
  for (int nd = 0; nd < 8; ++nd)
#pragma unroll
    for (int j = 0; j < 4; ++j)
      Obuf[w * 2112 + (lg * 4 + j) * 132 + nd * 16 + l15] = o[nd][j];
  __syncthreads();
  {
    float al[4][4], Lt[4];
#pragma unroll
    for (int j = 0; j < 4; ++j) {
      int q = lg * 4 + j;
      float M = Mlds[q];
#pragma unroll
      for (int ww = 1; ww < 4; ++ww) M = fmaxf(M, Mlds[ww * 16 + q]);
      float sL = 0.f;
#pragma unroll
      for (int ww = 0; ww < 4; ++ww) {
        float aa = exp2f(Mlds[ww * 16 + q] - M);
        al[ww][j] = aa; sL += aa * Llds[ww * 16 + q];
      }
      Lt[j] = sL;
    }
#pragma unroll
    for (int t2 = 0; t2 < 2; ++t2) {
      int nd = w * 2 + t2;
#pragma unroll
      for (int j = 0; j < 4; ++j) {
        int q = lg * 4 + j;
        float acc2 = 0.f;
#pragma unroll
        for (int ww = 0; ww < 4; ++ww)
          acc2 += al[ww][j] * Obuf[ww * 2112 + q * 132 + nd * 16 + l15];
        out[(bbase + q0 + q) * DH + nd * 16 + l15] = acc2 / Lt[j];
      }
    }
  }
}

extern "C" void kernel_launch(void* const* d_in, const int* in_sizes, int n_in,
                              void* d_out, int out_size, void* d_ws, size_t ws_size,
                              hipStream_t stream) {
  const float* x    = (const float*)d_in[0];
  const float* wq   = (const float*)d_in[1];
  const float* bq   = (const float*)d_in[2];
  const float* wk   = (const float*)d_in[3];
  const float* bk   = (const float*)d_in[4];
  const float* wv   = (const float*)d_in[5];
  const float* bv   = (const float*)d_in[6];
  const float* sing = (const float*)d_in[7];
  const float* cosg = (const float*)d_in[8];
  float* out = (float*)d_out;

  char* ws = (char*)d_ws;
  unsigned short* wb = (unsigned short*)ws;                        // 3,145,728 B
  float* biasws = (float*)(ws + 3145728);                          // 1,536 B
  unsigned short* qb = (unsigned short*)(ws + 3147264);            // 4 MB
  unsigned short* kb = (unsigned short*)(ws + 3147264 + 4194304);  // 4 MB
  unsigned short* vt = (unsigned short*)(ws + 3147264 + 2 * 4194304);  // 4 MB (V^T)
  // total ws use: ~15.7 MB

  cast_w_kernel<<<768, 256, 0, stream>>>(wq, wk, wv, bq, bk, bv, wb, biasws);
  gemm_qkv_rope<<<768, 256, 0, stream>>>(x, wb, biasws, sing, cosg, qb, kb, vt);
  attn_kernel<<<1024, 256, 0, stream>>>(qb, kb, vt, out);
}

// Round 14
// 176.955 us; speedup vs baseline: 1.6452x; 1.2868x over previous
//
#include <hip/hip_runtime.h>
#include <hip/hip_bf16.h>
#include <float.h>
#include <math.h>

typedef float f32x4 __attribute__((ext_vector_type(4)));
typedef short short8 __attribute__((ext_vector_type(8)));
typedef unsigned int uint32;

#define NB 4
#define SQ 4096
#define DM 4096
#define DH 128
#define LOG2E 1.44269504088896f
#define SCALE 0.0883883476483184f   // 1/sqrt(128)
#define SCL2 (SCALE * LOG2E)        // fold into log2 domain

__device__ __forceinline__ unsigned short f2bf(float f) {
  union { float f; unsigned u; } x; x.f = f;
  unsigned r = x.u + 0x7FFFu + ((x.u >> 16) & 1u);
  return (unsigned short)(r >> 16);
}

__device__ __forceinline__ uint2 cvt4(float4 f) {
  uint2 u;
  asm("v_cvt_pk_bf16_f32 %0, %1, %2" : "=v"(u.x) : "v"(f.x), "v"(f.y));
  asm("v_cvt_pk_bf16_f32 %0, %1, %2" : "=v"(u.y) : "v"(f.z), "v"(f.w));
  return u;
}

#define GLD16(g, l) __builtin_amdgcn_global_load_lds( \
    (const __attribute__((address_space(1))) void*)(g), \
    (__attribute__((address_space(3))) void*)(l), 16, 0, 0)

// ---------------- kernel 1: pack weights (bf16) + bias (f32) ----------------
__global__ void cast_w_kernel(const float* __restrict__ wq, const float* __restrict__ wk,
                              const float* __restrict__ wv, const float* __restrict__ bq,
                              const float* __restrict__ bk, const float* __restrict__ bv,
                              unsigned short* __restrict__ wb, float* __restrict__ biasws) {
  int t = blockIdx.x * 256 + threadIdx.x;  // 0..196607, each handles 8 elems
  int base = t * 8;
  int n = base >> 12;       // output row 0..383 (q:0-127, k:128-255, v:256-383)
  int d = base & 4095;
  const float* src = (n < 128) ? (wq + (size_t)n * DM)
                   : (n < 256) ? (wk + (size_t)(n - 128) * DM)
                               : (wv + (size_t)(n - 256) * DM);
  float4 f0 = *(const float4*)(src + d);
  float4 f1 = *(const float4*)(src + d + 4);
  short8 v;
  v[0] = (short)f2bf(f0.x); v[1] = (short)f2bf(f0.y);
  v[2] = (short)f2bf(f0.z); v[3] = (short)f2bf(f0.w);
  v[4] = (short)f2bf(f1.x); v[5] = (short)f2bf(f1.y);
  v[6] = (short)f2bf(f1.z); v[7] = (short)f2bf(f1.w);
  *(short8*)(wb + base) = v;
  if (t < 384) biasws[t] = (t < 128) ? bq[t] : (t < 256) ? bk[t - 128] : bv[t - 256];
}

// ---------------- kernel 2: fused QKV GEMM + bias + RoPE (+ V^T store) ------
// R8 structure (best measured: 150 us) -- frozen after 7 falsified rewrites.
__global__ __launch_bounds__(256) void gemm_qkv_rope(
    const float* __restrict__ x, const unsigned short* __restrict__ wb,
    const float* __restrict__ biasws, const float* __restrict__ sing,
    const float* __restrict__ cosg, unsigned short* __restrict__ qb,
    unsigned short* __restrict__ kb, unsigned short* __restrict__ vt) {
  __shared__ __align__(16) short Alds[2 * 64 * 64];
  __shared__ __align__(16) short Blds[2 * 128 * 64];
  const int tid = threadIdx.x;
  const int l = tid & 63, w = tid >> 6;
  const int wm = w >> 1, wn = w & 1;
  const int l15 = l & 15, lg = l >> 4;
  const int bid = blockIdx.x;
  const int xcd = bid & 7, j = bid >> 3;
  const int mloc = j / 3, head = j - mloc * 3;
  const int m0 = (xcd * 32 + mloc) * 64;
  f32x4 acc[2][4] = {};
  const int ar0 = tid >> 4, ac4 = (tid & 15) * 4;
  const float* xsrc = x + (size_t)(m0 + ar0) * DM + ac4;
  const int achunk = (tid & 15) >> 1, ahalf = tid & 1;
  const int brow_ = tid >> 3, bchunk = tid & 7;
  const unsigned short* wbh = wb + (size_t)head * 128 * DM;
  float4 a00, a01, a02, a03, a10, a11, a12, a13;
  {
#pragma unroll
    for (int i = 0; i < 4; ++i) {
      float4 f = *(const float4*)(xsrc + (size_t)i * 16 * DM);
      int row = ar0 + i * 16;
      *(uint2*)&Alds[row * 64 + ((achunk ^ (row & 7)) * 8) + ahalf * 4] = cvt4(f);
    }
#pragma unroll
    for (int i = 0; i < 4; ++i) {
      int row = i * 32 + brow_;
      int slot = i * 256 + tid;
      GLD16(wbh + (size_t)row * DM + ((bchunk ^ (row & 7)) * 8), (char*)Blds + slot * 16);
    }
    a00 = *(const float4*)(xsrc + 64);
    a01 = *(const float4*)(xsrc + (size_t)16 * DM + 64);
    a02 = *(const float4*)(xsrc + (size_t)32 * DM + 64);
    a03 = *(const float4*)(xsrc + (size_t)48 * DM + 64);
  }
  auto giter = [&](int t, int CUR,
                   float4& n0, float4& n1, float4& n2, float4& n3,
                   float4& f0, float4& f1, float4& f2, float4& f3) {
    asm volatile("s_waitcnt vmcnt(4) lgkmcnt(0)" ::: "memory");
    __builtin_amdgcn_sched_barrier(0);
    __builtin_amdgcn_s_barrier();
    __builtin_amdgcn_sched_barrier(0);
    const int kB = (t + 1) * 64;
    char* bdst = (char*)Blds + (CUR ^ 1) * 16384;
#pragma unroll
    for (int i = 0; i < 4; ++i) {
      int row = i * 32 + brow_;
      int slot = i * 256 + tid;
      GLD16(wbh + (size_t)row * DM + kB + ((bchunk ^ (row & 7)) * 8), bdst + slot * 16);
    }
    __builtin_amdgcn_sched_barrier(0);
    const int kF = (t < 62) ? (t + 2) * 64 : 0;
    f0 = *(const float4*)(xsrc + kF);
    f1 = *(const float4*)(xsrc + (size_t)16 * DM + kF);
    f2 = *(const float4*)(xsrc + (size_t)32 * DM + kF);
    f3 = *(const float4*)(xsrc + (size_t)48 * DM + kF);
#pragma unroll
    for (int kc = 0; kc < 2; ++kc) {
      short8 af[2], bfr[4];
#pragma unroll
      for (int mi = 0; mi < 2; ++mi) {
        int r = wm * 32 + mi * 16 + l15;
        af[mi] = *(short8*)&Alds[CUR * 4096 + r * 64 + ((kc * 32 + lg * 8) ^ ((r & 7) << 3))];
      }
#pragma unroll
      for (int ni = 0; ni < 4; ++ni) {
        int r = wn * 64 + ni * 16 + l15;
        bfr[ni] = *(short8*)&Blds[CUR * 8192 + r * 64 + ((kc * 32 + lg * 8) ^ ((r & 7) << 3))];
      }
#pragma unroll
      for (int mi = 0; mi < 2; ++mi)
#pragma unroll
        for (int ni = 0; ni < 4; ++ni)
          acc[mi][ni] = __builtin_amdgcn_mfma_f32_16x16x32_bf16(af[mi], bfr[ni], acc[mi][ni], 0, 0, 0);
    }
    short* Adst = &Alds[(CUR ^ 1) * 4096];
    int r0 = ar0, r1 = ar0 + 16, r2 = ar0 + 32, r3 = ar0 + 48;
    *(uint2*)&Adst[r0 * 64 + ((achunk ^ (r0 & 7)) * 8) + ahalf * 4] = cvt4(n0);
    *(uint2*)&Adst[r1 * 64 + ((achunk ^ (r1 & 7)) * 8) + ahalf * 4] = cvt4(n1);
    *(uint2*)&Adst[r2 * 64 + ((achunk ^ (r2 & 7)) * 8) + ahalf * 4] = cvt4(n2);
    *(uint2*)&Adst[r3 * 64 + ((achunk ^ (r3 & 7)) * 8) + ahalf * 4] = cvt4(n3);
  };
#pragma unroll 1
  for (int t = 0; t < 62; t += 2) {
    giter(t, 0, a00, a01, a02, a03, a10, a11, a12, a13);
    giter(t + 1, 1, a10, a11, a12, a13, a00, a01, a02, a03);
  }
  giter(62, 0, a00, a01, a02, a03, a10, a11, a12, a13);
  {
    asm volatile("s_waitcnt vmcnt(0) lgkmcnt(0)" ::: "memory");
    __builtin_amdgcn_sched_barrier(0);
    __builtin_amdgcn_s_barrier();
    __builtin_amdgcn_sched_barrier(0);
#pragma unroll
    for (int kc = 0; kc < 2; ++kc) {
      short8 af[2], bfr[4];
#pragma unroll
      for (int mi = 0; mi < 2; ++mi) {
        int r = wm * 32 + mi * 16 + l15;
        af[mi] = *(short8*)&Alds[4096 + r * 64 + ((kc * 32 + lg * 8) ^ ((r & 7) << 3))];
      }
#pragma unroll
      for (int ni = 0; ni < 4; ++ni) {
        int r = wn * 64 + ni * 16 + l15;
        bfr[ni] = *(short8*)&Blds[8192 + r * 64 + ((kc * 32 + lg * 8) ^ ((r & 7) << 3))];
      }
#pragma unroll
      for (int mi = 0; mi < 2; ++mi)
#pragma unroll
        for (int ni = 0; ni < 4; ++ni)
          acc[mi][ni] = __builtin_amdgcn_mfma_f32_16x16x32_bf16(af[mi], bfr[ni], acc[mi][ni], 0, 0, 0);
    }
  }
  if (head == 2) {
    unsigned short* vtb = vt + (size_t)(m0 >> 12) * DH * SQ;
    const int srow = (m0 & (SQ - 1)) + wm * 32;
#pragma unroll
    for (int mi = 0; mi < 2; ++mi)
#pragma unroll
      for (int ni = 0; ni < 4; ++ni) {
        int h = wn * 64 + ni * 16 + l15;
        float bias = biasws[256 + h];
        f32x4 a = acc[mi][ni];
        float4 f;
        f.x = a[0] + bias; f.y = a[1] + bias; f.z = a[2] + bias; f.w = a[3] + bias;
        *(uint2*)&vtb[(size_t)h * SQ + srow + mi * 16 + lg * 4] = cvt4(f);
      }
  } else {
    unsigned short* dst = (head == 0) ? qb : kb;
#pragma unroll
    for (int mi = 0; mi < 2; ++mi)
#pragma unroll
      for (int ni = 0; ni < 4; ++ni) {
        int h = wn * 64 + ni * 16 + l15;
        float bias = biasws[head * 128 + h];
        f32x4 a = acc[mi][ni];
#pragma unroll
        for (int j2 = 0; j2 < 4; ++j2) {
          int row = m0 + wm * 32 + mi * 16 + lg * 4 + j2;
          float val = a[j2] + bias;
          int s = row & (SQ - 1);
          float cs = cosg[s * DH + h];
          float sn = sing[s * DH + h];
          float pr = __shfl_xor(val, 1, 64);
          float sw = (l & 1) ? val : pr;
          val = val * cs + sw * sn;
          dst[(size_t)row * DH + h] = f2bf(val);
        }
      }
  }
}

// ---------------- kernel 3: causal flash attention, QBLK=32 ----------------
// 512 blocks x 4 waves: wave = (qsub = w>>1) x (ksplit = w&1). Each ksplit
// pair stages K[64][128] + V^T[128][64] (32 KB) into its own LDS buffer via
// GLD16 (pre-swizzled source, linear dest); BOTH qsub waves consume it ->
// KV L2 traffic HALVED vs QBLK=16 (263 -> 132 MB/batch). 2 blocks/CU
// (75.5 KB LDS), 8 waves/CU; stage latency covered by co-resident block.
// Swapped QK^T, in-lane softmax, log2 domain, defer-max. 2-way end merge
// (Obuf aliases the KV region after the loop).
__global__ __launch_bounds__(256) void attn_kernel(
    const unsigned short* __restrict__ qb, const unsigned short* __restrict__ kb,
    const unsigned short* __restrict__ vt, float* __restrict__ out) {
  __shared__ __align__(16) short KV[4 * 8192];        // K[2][64][128] | V[2][128][64], 64 KB
  __shared__ __align__(16) short Plds4[4 * 1152];     // per-wave P staging, 9 KB
  __shared__ __align__(16) float Mlds[64];
  __shared__ __align__(16) float Llds[64];
  __shared__ __align__(16) float Clds[64];
  const int tid = threadIdx.x;
  const int w = tid >> 6, l = tid & 63;
  const int qsub = w >> 1, ksp = w & 1;
  const int l15 = l & 15, lg = l >> 4;

  // schedule: slot = XCD (bi&7); batch = slot>>1 (KV 2MB in 4MB L2); p5 picks
  // tile half; zigzag pairs (t, 127-t) balance per-slot step totals.
  const int bi = blockIdx.x;
  const int slot = bi & 7, p5 = slot & 1, batch = slot >> 1;
  const int a = bi >> 3;  // 0..63
  const int t = (a & 1) ? (127 - p5 * 32 - (a >> 1)) : (p5 * 32 + (a >> 1));
  const int q0 = t * 32;
  const int qb0 = q0 + qsub * 16;
  const size_t bbase = (size_t)batch * SQ;
  const unsigned short* Kb = kb + bbase * DH;
  const unsigned short* Vtb = vt + (size_t)batch * DH * SQ;

  short* Kp = KV + ksp * 8192;            // [64][128] bf16, chunk^(row&15)
  short* Vp = KV + 16384 + ksp * 8192;    // [128][64] bf16, chunk^(row&7)
  short* Pw = Plds4 + w * 1152;           // [16][72]

  // pair-local thread id: pair ksp = waves {ksp, ksp+2} -> ti = qsub*64 + l
  const int ti = qsub * 64 + l;
  const int krow_ = ti >> 4, kc_ = ti & 15;   // K stage: row i*8+krow_, chunk kc_
  const int vrow_ = ti >> 3, vc_ = ti & 7;    // V stage: row i*16+vrow_, chunk vc_

  short8 qf[4];
  {
    const unsigned short* qp = qb + (bbase + qb0 + l15) * DH + lg * 8;
#pragma unroll
    for (int kcd = 0; kcd < 4; ++kcd) qf[kcd] = *(const short8*)(qp + kcd * 32);
  }

  const int nsteps = (q0 + 32 + 63) >> 6;      // block staging steps
  const int nsteps_w = (qb0 + 16 + 63) >> 6;   // this wave's compute steps
  const int max_nit = (nsteps + 1) >> 1;

  float m_r = -INFINITY, l_r = 0.f;
  f32x4 o[8] = {};

  for (int it = 0; it < max_nit; ++it) {
    const int st = it * 2 + ksp;
    const int kv0 = st * 64;
    if (st < nsteps) {  // stage this pair's step (both waves of pair)
#pragma unroll
      for (int i = 0; i < 8; ++i) {
        int row = i * 8 + krow_;
        GLD16(Kb + (size_t)(kv0 + row) * DH + ((kc_ ^ (row & 15)) * 8),
              (char*)Kp + (i * 128 + ti) * 16);
      }
#pragma unroll
      for (int i = 0; i < 8; ++i) {
        int row = i * 16 + vrow_;
        GLD16(Vtb + (size_t)row * SQ + kv0 + ((vc_ ^ (row & 7)) * 8),
              (char*)Vp + (i * 128 + ti) * 16);
      }
    }
    asm volatile("s_waitcnt vmcnt(0)" ::: "memory");
    __builtin_amdgcn_s_barrier();   // stage complete for both pairs

    if (st < nsteps_w) {
      // --- QK^T from Kp: A-frag row=kv, k=d ---
      f32x4 sf[4] = {};
      __builtin_amdgcn_s_setprio(1);
#pragma unroll
      for (int kcd = 0; kcd < 4; ++kcd)
#pragma unroll
        for (int ni = 0; ni < 4; ++ni) {
          int r = ni * 16 + l15;
          short8 kf = *(short8*)&Kp[r * 128 + (((kcd * 4 + lg) ^ (r & 15)) * 8)];
          sf[ni] = __builtin_amdgcn_mfma_f32_16x16x32_bf16(kf, qf[kcd], sf[ni], 0, 0, 0);
        }
      __builtin_amdgcn_s_setprio(0);

      // --- scale (log2) + mask on diagonal step ---
      float s[4][4];
      if (st == nsteps_w - 1) {
#pragma unroll
        for (int ni = 0; ni < 4; ++ni)
#pragma unroll
          for (int j = 0; j < 4; ++j) {
            float v = sf[ni][j] * SCL2;
            if (kv0 + ni * 16 + lg * 4 + j > qb0 + l15) v = -FLT_MAX;
            s[ni][j] = v;
          }
      } else {
#pragma unroll
        for (int ni = 0; ni < 4; ++ni)
#pragma unroll
          for (int j = 0; j < 4; ++j) s[ni][j] = sf[ni][j] * SCL2;
      }

      // --- softmax: in-lane max over 16 + 2 shuffles ---
      float tmx = s[0][0];
#pragma unroll
      for (int ni = 0; ni < 4; ++ni)
#pragma unroll
        for (int j = 0; j < 4; ++j) tmx = fmaxf(tmx, s[ni][j]);
      tmx = fmaxf(tmx, __shfl_xor(tmx, 16, 64));
      tmx = fmaxf(tmx, __shfl_xor(tmx, 32, 64));

      if (__any(tmx > m_r + 8.0f)) {
        float mnew = fmaxf(m_r, tmx);
        float corr = exp2f(m_r - mnew);
        if (l < 16) Clds[w * 16 + l] = corr;
        l_r *= corr; m_r = mnew;
        f32x4 c4 = *(f32x4*)&Clds[w * 16 + lg * 4];
#pragma unroll
        for (int nd = 0; nd < 8; ++nd)
#pragma unroll
          for (int j = 0; j < 4; ++j) o[nd][j] *= c4[j];
      }

      float rs = 0.f;
      float pp[4][4];
#pragma unroll
      for (int ni = 0; ni < 4; ++ni)
#pragma unroll
        for (int j = 0; j < 4; ++j) {
          pp[ni][j] = exp2f(s[ni][j] - m_r);
          rs += pp[ni][j];
        }
      rs += __shfl_xor(rs, 16, 64);
      rs += __shfl_xor(rs, 32, 64);
      l_r += rs;

      // --- P -> bf16 -> A-frag layout via per-wave LDS ---
#pragma unroll
      for (int ni = 0; ni < 4; ++ni) {
        uint32 lo, hi;
        asm volatile("v_cvt_pk_bf16_f32 %0, %1, %2" : "=v"(lo) : "v"(pp[ni][0]), "v"(pp[ni][1]));
        asm volatile("v_cvt_pk_bf16_f32 %0, %1, %2" : "=v"(hi) : "v"(pp[ni][2]), "v"(pp[ni][3]));
        uint2 u; u.x = lo; u.y = hi;
        *(uint2*)&Pw[l15 * 72 + ni * 16 + lg * 4] = u;
      }
      short8 pa0 = *(short8*)&Pw[l15 * 72 + lg * 8];
      short8 pa1 = *(short8*)&Pw[l15 * 72 + 32 + lg * 8];

      // --- PV from Vp: B-frag col=d(row of V^T), k=s ---
      __builtin_amdgcn_s_setprio(1);
#pragma unroll
      for (int nd = 0; nd < 8; ++nd) {
        int r = nd * 16 + l15;
        short8 v0 = *(short8*)&Vp[r * 64 + ((lg ^ (r & 7)) * 8)];
        short8 v1 = *(short8*)&Vp[r * 64 + (((lg + 4) ^ (r & 7)) * 8)];
        o[nd] = __builtin_amdgcn_mfma_f32_16x16x32_bf16(pa0, v0, o[nd], 0, 0, 0);
        o[nd] = __builtin_amdgcn_mfma_f32_16x16x32_bf16(pa1, v1, o[nd], 0, 0, 0);
      }
      __builtin_amdgcn_s_setprio(0);
    }
    __builtin_amdgcn_s_barrier();   // compute done before next stage overwrite
  }

  // --- 2-way merge across the ksplit pair (waves w and w^1, same qsub) ---
  if (l < 16) { Mlds[w * 16 + l] = m_r; Llds[w * 16 + l] = l_r; }
  __syncthreads();                  // M/L visible; KV region now reusable
  float* Ob = (float*)KV;           // 4 waves x 2112 floats = 33 KB (fits)
#pragma unroll
  for (int nd = 0; nd < 8; ++nd)
#pragma unroll
    for (int j = 0; j < 4; ++j)
      Ob[w * 2112 + (lg * 4 + j) * 132 + nd * 16 + l15] = o[nd][j];
  __syncthreads();
  {
    const int w0 = qsub * 2, w1 = qsub * 2 + 1;
    float al0[4], al1[4], Lt[4];
#pragma unroll
    for (int j = 0; j < 4; ++j) {
      int q = lg * 4 + j;
      float ma = Mlds[w0 * 16 + q], mb = Mlds[w1 * 16 + q];
      float M = fmaxf(ma, mb);
      al0[j] = exp2f(ma - M); al1[j] = exp2f(mb - M);
      Lt[j] = al0[j] * Llds[w0 * 16 + q] + al1[j] * Llds[w1 * 16 + q];
    }
#pragma unroll
    for (int t2 = 0; t2 < 4; ++t2) {
      int nd = ksp * 4 + t2;
#pragma unroll
      for (int j = 0; j < 4; ++j) {
        int q = lg * 4 + j;
        float acc2 = al0[j] * Ob[w0 * 2112 + q * 132 + nd * 16 + l15]
                   + al1[j] * Ob[w1 * 2112 + q * 132 + nd * 16 + l15];
        out[(bbase + qb0 + q) * DH + nd * 16 + l15] = acc2 / Lt[j];
      }
    }
  }
}

extern "C" void kernel_launch(void* const* d_in, const int* in_sizes, int n_in,
                              void* d_out, int out_size, void* d_ws, size_t ws_size,
                              hipStream_t stream) {
  const float* x    = (const float*)d_in[0];
  const float* wq   = (const float*)d_in[1];
  const float* bq   = (const float*)d_in[2];
  const float* wk   = (const float*)d_in[3];
  const float* bk   = (const float*)d_in[4];
  const float* wv   = (const float*)d_in[5];
  const float* bv   = (const float*)d_in[6];
  const float* sing = (const float*)d_in[7];
  const float* cosg = (const float*)d_in[8];
  float* out = (float*)d_out;

  char* ws = (char*)d_ws;
  unsigned short* wb = (unsigned short*)ws;                        // 3,145,728 B
  float* biasws = (float*)(ws + 3145728);                          // 1,536 B
  unsigned short* qb = (unsigned short*)(ws + 3147264);            // 4 MB
  unsigned short* kb = (unsigned short*)(ws + 3147264 + 4194304);  // 4 MB
  unsigned short* vt = (unsigned short*)(ws + 3147264 + 2 * 4194304);  // 4 MB (V^T)
  // total ws use: ~15.7 MB

  cast_w_kernel<<<768, 256, 0, stream>>>(wq, wk, wv, bq, bk, bv, wb, biasws);
  gemm_qkv_rope<<<768, 256, 0, stream>>>(x, wb, biasws, sing, cosg, qb, kb, vt);
  attn_kernel<<<512, 256, 0, stream>>>(qb, kb, vt, out);
}